// Round 5
// baseline (210.614 us; speedup 1.0000x reference)
//
#include <hip/hip_runtime.h>
#include <math.h>

// QueryEmb: B=4,L=512,D=512,V=32000, 4 segments of 8000, TEMP=sqrt(512).
// Equivalences: (1) masked softmax == softmax over token's own segment only;
// (2) |scores|<=~0.35 -> exp() safe without max-subtraction -> plain-sum
//     denoms and trivially split-K PV.
// R15: phase-halving. Evidence: 4 schedules x {3,4,5} blocks/CU all pin
// k_qk at 41us with 8 barrier-phases/block; k_pv ~40us at the same
// phases/CU (34 vs 35). Per-phase cost ~2800 cyc is schedule- and
// occupancy-invariant -> fixed latency floor per barrier phase. So: halve
// phases. BK=128 (64 MFMA/phase), separate sA/sB 16KB, reg-staged
// (8x global dwordx4 -> vmcnt(0) after compute -> 8x ds_write_b128),
// double-buffered, 64KB LDS, 2 blk/CU. k_qk: 4 phases; k_pv: 8 (z<7)/7.
// Also: k_final rewritten token-major (iperm table from prep) -> coalesced
// float4 out-writes instead of 4B/lane scatter to 64 lines per wave.

constexpr int Dm   = 512;
constexpr int SEG  = 8000;
constexpr int PSTR = 8064;            // P row stride (63*128), pad rows zeroed
constexpr int NTOK = 2048;
constexpr int TIL  = 128;             // slot tile
constexpr int MAXTILES = 20;          // 2048/128 + 4 pad
constexpr int MAXSLOTS = MAXTILES * TIL;   // 2560

// ws layout (bytes)
constexpr size_t WS_DENOM = 0;                                   // 2048 f32
constexpr size_t WS_META  = 8192;                                // 8 int
constexpr size_t WS_PERM  = 8448;                                // 2560 int (ends 18688)
constexpr size_t WS_IPERM = 20480;                               // 2048 int (ends 28672)
constexpr size_t WS_QB8   = 32768;                               // fp8 [2560][512]
constexpr size_t WS_EB8   = WS_QB8 + (size_t)MAXSLOTS * Dm;      // fp8 [32000][512]
constexpr size_t WS_OACC  = WS_EB8 + (size_t)32000 * Dm;         // bf16 [8][512][2560]
constexpr size_t WS_ET8   = WS_OACC + (size_t)8 * Dm * MAXSLOTS * 2;  // fp8 [512][32000]
constexpr size_t WS_P8    = WS_ET8 + (size_t)Dm * 32000;         // fp8 [2560][8064]
// total ~75.7 MB (< proven 104 MB)

typedef __attribute__((ext_vector_type(4))) float f32x4;
typedef __attribute__((ext_vector_type(4))) unsigned int u32x4;
#define LDSP __attribute__((address_space(3)))
typedef LDSP unsigned char lds_u8;
typedef LDSP u32x4 lds_v4;

static __device__ __forceinline__ ushort f2bf(float f) {
    union { float f; unsigned u; } v; v.f = f;
    unsigned r = v.u + 0x7FFF + ((v.u >> 16) & 1);   // RNE
    return (ushort)(r >> 16);
}
static __device__ __forceinline__ float bf2f(ushort u) {
    union { unsigned u; float f; } v; v.u = ((unsigned)u) << 16;
    return v.f;
}
// pack 4 floats -> 4 OCP fp8 e4m3 bytes (byte0 = a .. byte3 = d)
static __device__ __forceinline__ int pack_fp8x4(float a, float b, float c, float d) {
    int r = __builtin_amdgcn_cvt_pk_fp8_f32(a, b, 0, false);
    r = __builtin_amdgcn_cvt_pk_fp8_f32(c, d, r, true);
    return r;
}

#define WAIT0 asm volatile("s_waitcnt vmcnt(0)" ::: "memory")
#define LGKM0 asm volatile("s_waitcnt lgkmcnt(0)" ::: "memory")
#define BARX  { __builtin_amdgcn_s_barrier(); __builtin_amdgcn_sched_barrier(0); }

// compute one BK=128 tile from (CA,CB): 4 k-chunks of 32, 16 MFMA each
#define CSTEP(CA, CB)                                                          \
    _Pragma("unroll")                                                          \
    for (int ks = 0; ks < 4; ++ks) {                                           \
        const int cg = ks*2 + (quad >> 1), ho = (quad & 1) * 8;                \
        long A[4], B[4];                                                       \
        _Pragma("unroll")                                                      \
        for (int m = 0; m < 4; ++m) {                                          \
            const int row = rh*64 + m*16 + l15;                                \
            A[m] = *(const LDSP long*)((CA) + (row*8 + (cg ^ (row & 7)))*16 + ho); \
        }                                                                      \
        _Pragma("unroll")                                                      \
        for (int n = 0; n < 4; ++n) {                                          \
            const int row = th*64 + n*16 + l15;                                \
            B[n] = *(const LDSP long*)((CB) + (row*8 + (cg ^ (row & 7)))*16 + ho); \
        }                                                                      \
        __builtin_amdgcn_s_setprio(1);                                         \
        _Pragma("unroll")                                                      \
        for (int m = 0; m < 4; ++m)                                            \
            _Pragma("unroll")                                                  \
            for (int n = 0; n < 4; ++n)                                        \
                acc[m][n] = __builtin_amdgcn_mfma_f32_16x16x32_fp8_fp8(A[m], B[n], acc[m][n], 0, 0, 0); \
        __builtin_amdgcn_s_setprio(0);                                         \
    }

// pipeline step: issue 8 loads for tile T, compute tile in (CA,CB), then
// wait + ds_write T into (NA,NB), one barrier.
#define PSTEP(CA, CB, NA, NB, T)                                               \
    {                                                                          \
        u32x4 sv[8];                                                           \
        _Pragma("unroll")                                                      \
        for (int i = 0; i < 4; ++i) {                                          \
            sv[i]   = *(const u32x4*)(srcA[i] + (size_t)(T)*128);              \
            sv[4+i] = *(const u32x4*)(srcB[i] + (size_t)(T)*128);              \
        }                                                                      \
        CSTEP(CA, CB)                                                          \
        WAIT0;                                                                 \
        _Pragma("unroll")                                                      \
        for (int i = 0; i < 4; ++i) {                                          \
            *(lds_v4*)((NA) + dst[i]) = sv[i];                                 \
            *(lds_v4*)((NB) + dst[i]) = sv[4+i];                               \
        }                                                                      \
        LGKM0; BARX;                                                           \
    }

#define PROLOG(DA, DB)                                                         \
    {                                                                          \
        u32x4 sv[8];                                                           \
        _Pragma("unroll")                                                      \
        for (int i = 0; i < 4; ++i) {                                          \
            sv[i]   = *(const u32x4*)(srcA[i]);                                \
            sv[4+i] = *(const u32x4*)(srcB[i]);                                \
        }                                                                      \
        WAIT0;                                                                 \
        _Pragma("unroll")                                                      \
        for (int i = 0; i < 4; ++i) {                                          \
            *(lds_v4*)((DA) + dst[i]) = sv[i];                                 \
            *(lds_v4*)((DB) + dst[i]) = sv[4+i];                               \
        }                                                                      \
        LGKM0; BARX;                                                           \
    }

// ---- K2(+K1): emb fp32 -> EB8 fp8 + ET8 fp8 transposed; last x-block: prep ----
__global__ __launch_bounds__(256)
void k_conv(const float* __restrict__ emb, unsigned char* __restrict__ EB8,
            unsigned char* __restrict__ ET8,
            const int* __restrict__ xr, int* __restrict__ meta,
            int* __restrict__ perm, int* __restrict__ iperm,
            float* __restrict__ denom) {
    __shared__ unsigned char sT[64 * 8 * 16];   // 8 KB
    const int tid = threadIdx.x;
    if (blockIdx.x == 250) {                    // fused k_prep (1 block)
        if (blockIdx.y != 0) return;
        __shared__ int cnt[4], base[5], cur[4];
        if (tid < 4) { cnt[tid] = 0; cur[tid] = 0; }
        __syncthreads();
        for (int t = tid; t < NTOK; t += 256) {
            atomicAdd(&cnt[xr[t]], 1);
            denom[t] = 0.f;
        }
        __syncthreads();
        if (tid == 0) {
            base[0] = 0;
            for (int r = 0; r < 4; ++r) base[r+1] = base[r] + ((cnt[r] + TIL - 1) / TIL) * TIL;
            for (int r = 0; r < 5; ++r) meta[r] = base[r];
        }
        __syncthreads();
        for (int s = tid; s < MAXSLOTS; s += 256) perm[s] = -1;
        __syncthreads();
        for (int t = tid; t < NTOK; t += 256) {
            int r = xr[t];
            int sl = base[r] + atomicAdd(&cur[r], 1);
            perm[sl] = t;
            iperm[t] = sl;
        }
        return;
    }
    const int r0 = blockIdx.x * 128, d0 = blockIdx.y * 64;
    {
        const int dq = tid & 15, ro = tid >> 4;     // 4-d group, 8-row group
        int p[8];
        #pragma unroll
        for (int i = 0; i < 8; ++i) {
            float4 v = *(const float4*)(emb + (size_t)(r0 + ro*8 + i) * Dm + d0 + dq*4);
            p[i] = pack_fp8x4(v.x, v.y, v.z, v.w);
            *(int*)(EB8 + (size_t)(r0 + ro*8 + i) * Dm + d0 + dq*4) = p[i];
        }
        const int gr = ro >> 1, half = ro & 1;
        #pragma unroll
        for (int j = 0; j < 4; ++j) {               // per d: pack 8 row-bytes
            const int d = dq*4 + j;
            unsigned long long t = 0;
            #pragma unroll
            for (int i = 0; i < 8; ++i)
                t |= ((unsigned long long)((p[i] >> (8*j)) & 0xff)) << (8*i);
            *(unsigned long long*)(sT + (d*8 + (gr ^ (d & 7))) * 16 + half * 8) = t;
        }
    }
    __syncthreads();
    {
        const int d = tid >> 2, rq = tid & 3;
        unsigned char* dst = ET8 + (size_t)(d0 + d) * 32000 + r0;
        #pragma unroll
        for (int b = 0; b < 2; ++b) {
            const int gr = rq * 2 + b;
            *(uint4*)(dst + gr * 16) = *(const uint4*)(sT + (d*8 + (gr ^ (d & 7))) * 16);
        }
    }
}

// ---- K2b: gather Q -> Qb8 fp8 [2560 slots][512] (pad slots zeroed) ----
__global__ __launch_bounds__(256)
void k_qb(const float* __restrict__ q, const int* __restrict__ perm,
          unsigned char* __restrict__ Qb8) {
    const int slot = blockIdx.x * 8 + (threadIdx.x >> 5);
    const int ln = threadIdx.x & 31;
    const int tok = perm[slot];
    #pragma unroll
    for (int j = 0; j < 4; ++j) {
        const int c4 = ln + j * 32;
        int p = 0;
        if (tok >= 0) {
            float4 v = ((const float4*)q)[(size_t)tok * 128 + c4];
            p = pack_fp8x4(v.x, v.y, v.z, v.w);
        }
        ((int*)(Qb8 + (size_t)slot * Dm))[c4] = p;
    }
}

// ---- K3: S^T = E.Q^T fp8, BK=128 reg-staged dbuf (4 phases); exp -> P8 ----
__global__ __launch_bounds__(256, 2)
void k_qk(const unsigned char* __restrict__ EB8, const unsigned char* __restrict__ Qb8,
          const int* __restrict__ meta, const int* __restrict__ perm,
          float* __restrict__ denom, unsigned char* __restrict__ P8) {
    __shared__ unsigned char sA0[128 * 128];   // 16 KB each: 128 rows x 128 B (BK=128)
    __shared__ unsigned char sB0[128 * 128];
    __shared__ unsigned char sA1[128 * 128];
    __shared__ unsigned char sB1[128 * 128];
    const int tid = threadIdx.x, lane = tid & 63, w = tid >> 6;
    const int g    = blockIdx.x & 7;              // XCD group
    const int rest = blockIdx.x >> 3;
    const int tt       = rest >> 3;               // tt-outer: tail blocks last
    const int rt_local = rest & 7;                // 0..7
    const int c = g * 8 + rt_local;               // row-tile 0..63
    const int slot0 = tt * TIL;
    const int b1 = meta[1], b2 = meta[2], b3 = meta[3], b4 = meta[4];
    if (slot0 >= b4) return;
    const int row0 = c * 128;
    if (row0 >= PSTR) return;                     // c==63: provably writes nothing
    const int rank = (slot0 >= b1) + (slot0 >= b2) + (slot0 >= b3);

    // per-thread staging map: granule gg = w*256 + i*64 + lane covers 0..1023
    // exactly; r = gg>>3 (LDS row), cg = gg&7 (content granule of the row's
    // 128-B k-slice); swizzled position = cg ^ (r&7).
    const unsigned char* srcA[4];
    const unsigned char* srcB[4];
    int dst[4];
    #pragma unroll
    for (int i = 0; i < 4; ++i) {
        const int gg = w * 256 + i * 64 + lane;
        const int r = gg >> 3, cg = gg & 7;
        int grow = row0 + r;
        if (grow >= SEG) grow = SEG - 1;          // clamp; outputs masked
        srcA[i] = EB8 + (size_t)rank * SEG * Dm + (size_t)grow * Dm + cg * 16;
        srcB[i] = Qb8 + (size_t)(slot0 + r) * Dm + cg * 16;
        dst[i]  = (r * 8 + (cg ^ (r & 7))) * 16;
    }
    const int rh = w >> 1, th = w & 1, quad = lane >> 4, l15 = lane & 15;
    const float invT = 0.04419417382415922f;   // 1/sqrt(512)
    lds_u8* a0 = (lds_u8*)sA0; lds_u8* b0 = (lds_u8*)sB0;
    lds_u8* a1 = (lds_u8*)sA1; lds_u8* b1p = (lds_u8*)sB1;

    f32x4 acc[4][4] = {};
    PROLOG(a0, b0)                    // tile 0 resident
    PSTEP(a0, b0, a1, b1p, 1)         // compute 0, stage 1
    PSTEP(a1, b1p, a0, b0, 2)         // compute 1, stage 2
    PSTEP(a0, b0, a1, b1p, 3)         // compute 2, stage 3
    CSTEP(a1, b1p)                    // compute 3

    float dsum[4] = {0.f, 0.f, 0.f, 0.f};
    #pragma unroll
    for (int m = 0; m < 4; ++m) {
        const int r4 = row0 + rh*64 + m*16 + quad*4;
        if (r4 < SEG) {
            #pragma unroll
            for (int n = 0; n < 4; ++n) {
                float e0 = __expf(acc[m][n][0] * invT);
                float e1 = __expf(acc[m][n][1] * invT);
                float e2 = __expf(acc[m][n][2] * invT);
                float e3 = __expf(acc[m][n][3] * invT);
                const int slot = slot0 + th*64 + n*16 + l15;
                *(int*)(P8 + (size_t)slot * PSTR + r4) = pack_fp8x4(e0, e1, e2, e3);
                dsum[n] += e0 + e1 + e2 + e3;
            }
        } else if (r4 < PSTR) {                // zero the pad rows (k_pv tail)
            #pragma unroll
            for (int n = 0; n < 4; ++n) {
                const int slot = slot0 + th*64 + n*16 + l15;
                *(int*)(P8 + (size_t)slot * PSTR + r4) = 0;
            }
        }
    }
    #pragma unroll
    for (int n = 0; n < 4; ++n) {
        float s = dsum[n];
        s += __shfl_xor(s, 16, 64);
        s += __shfl_xor(s, 32, 64);
        if (quad == 0) {
            const int tok = perm[slot0 + th*64 + n*16 + l15];
            if (tok >= 0) atomicAdd(denom + tok, s);
        }
    }
}

// ---- K4: O^T = E^T.P^T fp8, BK=128 reg-staged dbuf (8/7 phases); z = XCD ----
__global__ __launch_bounds__(256, 2)
void k_pv(const unsigned char* __restrict__ ET8, const unsigned char* __restrict__ P8,
          const int* __restrict__ meta, ushort* __restrict__ Oacc) {
    __shared__ unsigned char sA0[128 * 128];
    __shared__ unsigned char sB0[128 * 128];
    __shared__ unsigned char sA1[128 * 128];
    __shared__ unsigned char sB1[128 * 128];
    const int tid = threadIdx.x, lane = tid & 63, w = tid >> 6;
    const int z    = blockIdx.x & 7;              // K-split == XCD group
    const int rest = blockIdx.x >> 3;
    const int tt   = rest >> 2;                   // tt-outer: tail blocks last
    const int dt   = rest & 3;                    // d-tile 0..3
    const int slot0 = tt * TIL;
    const int b1 = meta[1], b2 = meta[2], b3 = meta[3], b4 = meta[4];
    if (slot0 >= b4) return;
    const int rank = (slot0 >= b1) + (slot0 >= b2) + (slot0 >= b3);
    const int d0 = dt * 128;
    const int kstart = z * 1024;
    const int nit = (z == 7) ? 7 : 8;             // BK=128: 7*8+7 = 63 -> 8064 rows

    const unsigned char* srcA[4];
    const unsigned char* srcB[4];
    int dst[4];
    #pragma unroll
    for (int i = 0; i < 4; ++i) {
        const int gg = w * 256 + i * 64 + lane;
        const int r = gg >> 3, cg = gg & 7;
        srcA[i] = ET8 + (size_t)(d0 + r) * 32000 + (size_t)rank * SEG + kstart + cg * 16;
        srcB[i] = P8 + (size_t)(slot0 + r) * PSTR + kstart + cg * 16;  // pad rows are 0
        dst[i]  = (r * 8 + (cg ^ (r & 7))) * 16;
    }
    const int rh = w >> 1, th = w & 1, quad = lane >> 4, l15 = lane & 15;
    lds_u8* cA = (lds_u8*)sA0; lds_u8* cB = (lds_u8*)sB0;
    lds_u8* nA = (lds_u8*)sA1; lds_u8* nB = (lds_u8*)sB1;

    f32x4 acc[4][4] = {};
    PROLOG(cA, cB)
    for (int t = 1; t < nit; ++t) {
        PSTEP(cA, cB, nA, nB, t)
        lds_u8* tp;
        tp = cA; cA = nA; nA = tp;
        tp = cB; cB = nB; nB = tp;
    }
    CSTEP(cA, cB)

    ushort* Oz = Oacc + (size_t)z * Dm * MAXSLOTS;
    #pragma unroll
    for (int m = 0; m < 4; ++m) {
        const int d4 = d0 + rh*64 + m*16 + quad*4;
        #pragma unroll
        for (int n = 0; n < 4; ++n) {
            const int slot = slot0 + th*64 + n*16 + l15;
            #pragma unroll
            for (int j = 0; j < 4; ++j)
                Oz[(size_t)(d4 + j) * MAXSLOTS + slot] = f2bf(acc[m][n][j]);
        }
    }
}

// ---- K5: token-major: out[tok][d] = (sum_z Oacc[z][d][iperm[tok]])/denom + q ----
__global__ __launch_bounds__(256)
void k_final(const float* __restrict__ q, const int* __restrict__ iperm,
             const float* __restrict__ denom, const ushort* __restrict__ Oacc,
             float* __restrict__ out) {
    const int tk = threadIdx.x >> 5;              // 8 tokens per block
    const int dl = threadIdx.x & 31;
    const int token = blockIdx.x * 8 + tk;
    const int s = iperm[token];
    const float inv = 1.0f / denom[token];
    const float* qrow = q + (size_t)token * Dm;
    float* orow = out + (size_t)token * Dm;
    #pragma unroll
    for (int dc = 0; dc < 4; ++dc) {
        const int d = dc * 128 + dl * 4;
        float v[4];
        #pragma unroll
        for (int j = 0; j < 4; ++j) {
            float a = 0.f;
            #pragma unroll
            for (int z = 0; z < 8; ++z)
                a += bf2f(Oacc[((size_t)z * Dm + d + j) * MAXSLOTS + s]);
            v[j] = a * inv + qrow[d + j];
        }
        float4 o; o.x = v[0]; o.y = v[1]; o.z = v[2]; o.w = v[3];
        *(float4*)(orow + d) = o;                 // coalesced: lane dl -> d=dl*4
    }
}

extern "C" void kernel_launch(void* const* d_in, const int* in_sizes, int n_in,
                              void* d_out, int out_size, void* d_ws, size_t ws_size,
                              hipStream_t stream) {
    const float* q   = (const float*)d_in[0];
    const int*   xr  = (const int*)d_in[1];
    const float* emb = (const float*)d_in[2];
    float* out = (float*)d_out;
    char* ws = (char*)d_ws;

    float*  denom        = (float*)(ws + WS_DENOM);
    int*    meta         = (int*)(ws + WS_META);
    int*    perm         = (int*)(ws + WS_PERM);
    int*    iperm        = (int*)(ws + WS_IPERM);
    unsigned char* Qb8   = (unsigned char*)(ws + WS_QB8);
    unsigned char* EB8   = (unsigned char*)(ws + WS_EB8);
    ushort* Oacc         = (ushort*)(ws + WS_OACC);
    unsigned char* ET8   = (unsigned char*)(ws + WS_ET8);
    unsigned char* P8    = (unsigned char*)(ws + WS_P8);

    k_conv<<<dim3(251, 8), 256, 0, stream>>>(emb, EB8, ET8, xr, meta, perm, iperm, denom);
    k_qb<<<MAXSLOTS / 8, 256, 0, stream>>>(q, perm, Qb8);
    k_qk<<<8 * 8 * MAXTILES, 256, 0, stream>>>(EB8, Qb8, meta, perm, denom, P8);
    k_pv<<<8 * 4 * MAXTILES, 256, 0, stream>>>(ET8, P8, meta, Oacc);
    k_final<<<NTOK / 8, 256, 0, stream>>>(q, iperm, denom, Oacc, out);
}

// Round 6
// 166.613 us; speedup vs baseline: 1.2641x; 1.2641x over previous
//
#include <hip/hip_runtime.h>
#include <math.h>

// QueryEmb: B=4,L=512,D=512,V=32000, 4 segments of 8000, TEMP=sqrt(512).
// Equivalences: (1) masked softmax == softmax over token's own segment only;
// (2) |scores|<=~0.35 -> exp() safe without max-subtraction -> plain-sum
//     denoms and trivially split-K PV.
// R16: epilogue overhaul. Six GEMM-schedule variants all pinned k_qk at
// ~41us -> the schedule was never the bottleneck; the invariant was the
// epilogue: 4B scatter stores to P8 (16 lines per wave-store) + 129K
// atomicAdds to an 8KB denom region. Now:
//  - k_qk: P-tile staged in LDS (16KB, XOR-swizzled), written to P8 in 4
//    fully-coalesced passes (full 64B lines); denom -> race-free partials
//    dpart[(c*2+rh)][slot] (plain coalesced stores, no atomics).
//  - k_pv: Oacc layout [z][slot][d]; per (m,n) one 8B store (4 bf16).
//  - k_final: token-major, Oacc reads now 8B contiguous; denom = 126-entry
//    dpart column sum via 32-lane shuffle reduce. (R15's k_final read
//    Oacc[z][d][s] at 2B/5KB-stride: 74MB fetch, 44us -> fixed.)
// GEMM cores unchanged from R15 (BK=128 reg-staged dbuf, 2 blk/CU).

constexpr int Dm   = 512;
constexpr int SEG  = 8000;
constexpr int PSTR = 8064;            // P row stride (63*128), pad rows zeroed
constexpr int NTOK = 2048;
constexpr int TIL  = 128;             // slot tile
constexpr int MAXTILES = 20;          // 2048/128 + 4 pad
constexpr int MAXSLOTS = MAXTILES * TIL;   // 2560

// ws layout (bytes)
constexpr size_t WS_META  = 8192;                                // 8 int
constexpr size_t WS_PERM  = 8448;                                // 2560 int
constexpr size_t WS_IPERM = 20480;                               // 2048 int
constexpr size_t WS_QB8   = 32768;                               // fp8 [2560][512]
constexpr size_t WS_EB8   = WS_QB8 + (size_t)MAXSLOTS * Dm;      // fp8 [32000][512]
constexpr size_t WS_OACC  = WS_EB8 + (size_t)32000 * Dm;         // bf16 [8][2560][512]
constexpr size_t WS_ET8   = WS_OACC + (size_t)8 * Dm * MAXSLOTS * 2;  // fp8 [512][32000]
constexpr size_t WS_P8    = WS_ET8 + (size_t)Dm * 32000;         // fp8 [2560][8064]
constexpr size_t WS_DPART = WS_P8 + (size_t)MAXSLOTS * PSTR;     // f32 [126][2560]
// total ~77 MB (< proven 104 MB)

typedef __attribute__((ext_vector_type(4))) float f32x4;
typedef __attribute__((ext_vector_type(4))) unsigned int u32x4;
#define LDSP __attribute__((address_space(3)))
typedef LDSP unsigned char lds_u8;
typedef LDSP u32x4 lds_v4;
typedef LDSP int lds_i32;

static __device__ __forceinline__ ushort f2bf(float f) {
    union { float f; unsigned u; } v; v.f = f;
    unsigned r = v.u + 0x7FFF + ((v.u >> 16) & 1);   // RNE
    return (ushort)(r >> 16);
}
static __device__ __forceinline__ float bf2f(ushort u) {
    union { unsigned u; float f; } v; v.u = ((unsigned)u) << 16;
    return v.f;
}
// pack 4 floats -> 4 OCP fp8 e4m3 bytes (byte0 = a .. byte3 = d)
static __device__ __forceinline__ int pack_fp8x4(float a, float b, float c, float d) {
    int r = __builtin_amdgcn_cvt_pk_fp8_f32(a, b, 0, false);
    r = __builtin_amdgcn_cvt_pk_fp8_f32(c, d, r, true);
    return r;
}

#define WAIT0 asm volatile("s_waitcnt vmcnt(0)" ::: "memory")
#define LGKM0 asm volatile("s_waitcnt lgkmcnt(0)" ::: "memory")
#define BARX  { __builtin_amdgcn_s_barrier(); __builtin_amdgcn_sched_barrier(0); }

// compute one BK=128 tile from (CA,CB): 4 k-chunks of 32, 16 MFMA each
#define CSTEP(CA, CB)                                                          \
    _Pragma("unroll")                                                          \
    for (int ks = 0; ks < 4; ++ks) {                                           \
        const int cg = ks*2 + (quad >> 1), ho = (quad & 1) * 8;                \
        long A[4], B[4];                                                       \
        _Pragma("unroll")                                                      \
        for (int m = 0; m < 4; ++m) {                                          \
            const int row = rh*64 + m*16 + l15;                                \
            A[m] = *(const LDSP long*)((CA) + (row*8 + (cg ^ (row & 7)))*16 + ho); \
        }                                                                      \
        _Pragma("unroll")                                                      \
        for (int n = 0; n < 4; ++n) {                                          \
            const int row = th*64 + n*16 + l15;                                \
            B[n] = *(const LDSP long*)((CB) + (row*8 + (cg ^ (row & 7)))*16 + ho); \
        }                                                                      \
        __builtin_amdgcn_s_setprio(1);                                         \
        _Pragma("unroll")                                                      \
        for (int m = 0; m < 4; ++m)                                            \
            _Pragma("unroll")                                                  \
            for (int n = 0; n < 4; ++n)                                        \
                acc[m][n] = __builtin_amdgcn_mfma_f32_16x16x32_fp8_fp8(A[m], B[n], acc[m][n], 0, 0, 0); \
        __builtin_amdgcn_s_setprio(0);                                         \
    }

// pipeline step: issue 8 loads for tile T, compute tile in (CA,CB), then
// wait + ds_write T into (NA,NB), one barrier.
#define PSTEP(CA, CB, NA, NB, T)                                               \
    {                                                                          \
        u32x4 sv[8];                                                           \
        _Pragma("unroll")                                                      \
        for (int i = 0; i < 4; ++i) {                                          \
            sv[i]   = *(const u32x4*)(srcA[i] + (size_t)(T)*128);              \
            sv[4+i] = *(const u32x4*)(srcB[i] + (size_t)(T)*128);              \
        }                                                                      \
        CSTEP(CA, CB)                                                          \
        WAIT0;                                                                 \
        _Pragma("unroll")                                                      \
        for (int i = 0; i < 4; ++i) {                                          \
            *(lds_v4*)((NA) + dst[i]) = sv[i];                                 \
            *(lds_v4*)((NB) + dst[i]) = sv[4+i];                               \
        }                                                                      \
        LGKM0; BARX;                                                           \
    }

#define PROLOG(DA, DB)                                                         \
    {                                                                          \
        u32x4 sv[8];                                                           \
        _Pragma("unroll")                                                      \
        for (int i = 0; i < 4; ++i) {                                          \
            sv[i]   = *(const u32x4*)(srcA[i]);                                \
            sv[4+i] = *(const u32x4*)(srcB[i]);                                \
        }                                                                      \
        WAIT0;                                                                 \
        _Pragma("unroll")                                                      \
        for (int i = 0; i < 4; ++i) {                                          \
            *(lds_v4*)((DA) + dst[i]) = sv[i];                                 \
            *(lds_v4*)((DB) + dst[i]) = sv[4+i];                               \
        }                                                                      \
        LGKM0; BARX;                                                           \
    }

// ---- K2(+K1): emb fp32 -> EB8 fp8 + ET8 fp8 transposed; last x-block: prep ----
__global__ __launch_bounds__(256)
void k_conv(const float* __restrict__ emb, unsigned char* __restrict__ EB8,
            unsigned char* __restrict__ ET8,
            const int* __restrict__ xr, int* __restrict__ meta,
            int* __restrict__ perm, int* __restrict__ iperm) {
    __shared__ unsigned char sT[64 * 8 * 16];   // 8 KB
    const int tid = threadIdx.x;
    if (blockIdx.x == 250) {                    // fused k_prep (1 block)
        if (blockIdx.y != 0) return;
        __shared__ int cnt[4], base[5], cur[4];
        if (tid < 4) { cnt[tid] = 0; cur[tid] = 0; }
        __syncthreads();
        for (int t = tid; t < NTOK; t += 256)
            atomicAdd(&cnt[xr[t]], 1);
        __syncthreads();
        if (tid == 0) {
            base[0] = 0;
            for (int r = 0; r < 4; ++r) base[r+1] = base[r] + ((cnt[r] + TIL - 1) / TIL) * TIL;
            for (int r = 0; r < 5; ++r) meta[r] = base[r];
        }
        __syncthreads();
        for (int s = tid; s < MAXSLOTS; s += 256) perm[s] = -1;
        __syncthreads();
        for (int t = tid; t < NTOK; t += 256) {
            int r = xr[t];
            int sl = base[r] + atomicAdd(&cur[r], 1);
            perm[sl] = t;
            iperm[t] = sl;
        }
        return;
    }
    const int r0 = blockIdx.x * 128, d0 = blockIdx.y * 64;
    {
        const int dq = tid & 15, ro = tid >> 4;     // 4-d group, 8-row group
        int p[8];
        #pragma unroll
        for (int i = 0; i < 8; ++i) {
            float4 v = *(const float4*)(emb + (size_t)(r0 + ro*8 + i) * Dm + d0 + dq*4);
            p[i] = pack_fp8x4(v.x, v.y, v.z, v.w);
            *(int*)(EB8 + (size_t)(r0 + ro*8 + i) * Dm + d0 + dq*4) = p[i];
        }
        const int gr = ro >> 1, half = ro & 1;
        #pragma unroll
        for (int j = 0; j < 4; ++j) {               // per d: pack 8 row-bytes
            const int d = dq*4 + j;
            unsigned long long t = 0;
            #pragma unroll
            for (int i = 0; i < 8; ++i)
                t |= ((unsigned long long)((p[i] >> (8*j)) & 0xff)) << (8*i);
            *(unsigned long long*)(sT + (d*8 + (gr ^ (d & 7))) * 16 + half * 8) = t;
        }
    }
    __syncthreads();
    {
        const int d = tid >> 2, rq = tid & 3;
        unsigned char* dst = ET8 + (size_t)(d0 + d) * 32000 + r0;
        #pragma unroll
        for (int b = 0; b < 2; ++b) {
            const int gr = rq * 2 + b;
            *(uint4*)(dst + gr * 16) = *(const uint4*)(sT + (d*8 + (gr ^ (d & 7))) * 16);
        }
    }
}

// ---- K2b: gather Q -> Qb8 fp8 [2560 slots][512] (pad slots zeroed) ----
__global__ __launch_bounds__(256)
void k_qb(const float* __restrict__ q, const int* __restrict__ perm,
          unsigned char* __restrict__ Qb8) {
    const int slot = blockIdx.x * 8 + (threadIdx.x >> 5);
    const int ln = threadIdx.x & 31;
    const int tok = perm[slot];
    #pragma unroll
    for (int j = 0; j < 4; ++j) {
        const int c4 = ln + j * 32;
        int p = 0;
        if (tok >= 0) {
            float4 v = ((const float4*)q)[(size_t)tok * 128 + c4];
            p = pack_fp8x4(v.x, v.y, v.z, v.w);
        }
        ((int*)(Qb8 + (size_t)slot * Dm))[c4] = p;
    }
}

// ---- K3: S^T = E.Q^T fp8, BK=128 reg-staged dbuf; LDS-staged epilogue ----
__global__ __launch_bounds__(256, 2)
void k_qk(const unsigned char* __restrict__ EB8, const unsigned char* __restrict__ Qb8,
          const int* __restrict__ meta, float* __restrict__ dpart,
          unsigned char* __restrict__ P8) {
    __shared__ unsigned char sA0[128 * 128];   // 16 KB each: 128 rows x 128 B (BK=128)
    __shared__ unsigned char sB0[128 * 128];
    __shared__ unsigned char sA1[128 * 128];
    __shared__ unsigned char sB1[128 * 128];
    const int tid = threadIdx.x, lane = tid & 63, w = tid >> 6;
    const int g    = blockIdx.x & 7;              // XCD group
    const int rest = blockIdx.x >> 3;
    const int tt       = rest >> 3;               // tt-outer: tail blocks last
    const int rt_local = rest & 7;                // 0..7
    const int c = g * 8 + rt_local;               // row-tile 0..63
    const int slot0 = tt * TIL;
    const int b1 = meta[1], b2 = meta[2], b3 = meta[3], b4 = meta[4];
    if (slot0 >= b4) return;
    const int row0 = c * 128;
    if (row0 >= PSTR) return;                     // c==63: provably writes nothing
    const int rank = (slot0 >= b1) + (slot0 >= b2) + (slot0 >= b3);

    const unsigned char* srcA[4];
    const unsigned char* srcB[4];
    int dst[4];
    #pragma unroll
    for (int i = 0; i < 4; ++i) {
        const int gg = w * 256 + i * 64 + lane;
        const int r = gg >> 3, cg = gg & 7;
        int grow = row0 + r;
        if (grow >= SEG) grow = SEG - 1;          // clamp; outputs masked
        srcA[i] = EB8 + (size_t)rank * SEG * Dm + (size_t)grow * Dm + cg * 16;
        srcB[i] = Qb8 + (size_t)(slot0 + r) * Dm + cg * 16;
        dst[i]  = (r * 8 + (cg ^ (r & 7))) * 16;
    }
    const int rh = w >> 1, th = w & 1, quad = lane >> 4, l15 = lane & 15;
    const float invT = 0.04419417382415922f;   // 1/sqrt(512)
    lds_u8* a0 = (lds_u8*)sA0; lds_u8* b0 = (lds_u8*)sB0;
    lds_u8* a1 = (lds_u8*)sA1; lds_u8* b1p = (lds_u8*)sB1;

    f32x4 acc[4][4] = {};
    PROLOG(a0, b0)                    // tile 0 resident
    PSTEP(a0, b0, a1, b1p, 1)         // compute 0, stage 1
    PSTEP(a1, b1p, a0, b0, 2)         // compute 1, stage 2
    PSTEP(a0, b0, a1, b1p, 3)         // compute 2, stage 3
    CSTEP(a1, b1p)                    // compute 3

    // ---- epilogue: exp -> LDS P-tile (fp8, int-swizzled), dsums in regs ----
    // pT logical [slot_l(128)][int r4i(32)]; stored int idx = r4i ^ ((slot_l&7)<<2)
    lds_i32* pT = (lds_i32*)sA0;      // 16 KB; sA0 free after PSTEP3's barrier
    float dsum[4] = {0.f, 0.f, 0.f, 0.f};
    #pragma unroll
    for (int m = 0; m < 4; ++m) {
        const int rloc = rh*64 + m*16 + quad*4;
        const int r4 = row0 + rloc;
        const int r4i = rloc >> 2;
        #pragma unroll
        for (int n = 0; n < 4; ++n) {
            const int slot_l = th*64 + n*16 + l15;
            int pv = 0;
            if (r4 < SEG) {
                float e0 = __expf(acc[m][n][0] * invT);
                float e1 = __expf(acc[m][n][1] * invT);
                float e2 = __expf(acc[m][n][2] * invT);
                float e3 = __expf(acc[m][n][3] * invT);
                pv = pack_fp8x4(e0, e1, e2, e3);
                dsum[n] += e0 + e1 + e2 + e3;
            }
            pT[slot_l * 32 + (r4i ^ ((slot_l & 7) << 2))] = pv;
        }
    }
    BARX;
    // coalesced P8 write: 4 passes; 8 lanes cover one slot-row's 128 B
    #pragma unroll
    for (int p = 0; p < 4; ++p) {
        const int sr = (tid >> 3) + p * 32;        // slot row 0..127
        const int c4 = (tid & 7) * 4;              // int col base
        const int i0 = sr * 32 + (c4 ^ ((sr & 7) << 2));
        u32x4 v = *(const LDSP u32x4*)(pT + i0);
        *(u32x4*)(P8 + (size_t)(slot0 + sr) * PSTR + row0 + (tid & 7) * 16) = v;
    }
    // race-free denom partials: [c*2+rh][slot]
    #pragma unroll
    for (int n = 0; n < 4; ++n) {
        float s = dsum[n];
        s += __shfl_xor(s, 16, 64);
        s += __shfl_xor(s, 32, 64);
        if (quad == 0)
            dpart[(size_t)(c * 2 + rh) * MAXSLOTS + slot0 + th*64 + n*16 + l15] = s;
    }
}

// ---- K4: O^T = E^T.P^T fp8, BK=128 reg-staged dbuf; Oacc[z][slot][d] ----
__global__ __launch_bounds__(256, 2)
void k_pv(const unsigned char* __restrict__ ET8, const unsigned char* __restrict__ P8,
          const int* __restrict__ meta, ushort* __restrict__ Oacc) {
    __shared__ unsigned char sA0[128 * 128];
    __shared__ unsigned char sB0[128 * 128];
    __shared__ unsigned char sA1[128 * 128];
    __shared__ unsigned char sB1[128 * 128];
    const int tid = threadIdx.x, lane = tid & 63, w = tid >> 6;
    const int z    = blockIdx.x & 7;              // K-split == XCD group
    const int rest = blockIdx.x >> 3;
    const int tt   = rest >> 2;                   // tt-outer: tail blocks last
    const int dt   = rest & 3;                    // d-tile 0..3
    const int slot0 = tt * TIL;
    const int b1 = meta[1], b2 = meta[2], b3 = meta[3], b4 = meta[4];
    if (slot0 >= b4) return;
    const int rank = (slot0 >= b1) + (slot0 >= b2) + (slot0 >= b3);
    const int d0 = dt * 128;
    const int kstart = z * 1024;
    const int nit = (z == 7) ? 7 : 8;             // BK=128: 7*8+7 = 63 -> 8064 rows

    const unsigned char* srcA[4];
    const unsigned char* srcB[4];
    int dst[4];
    #pragma unroll
    for (int i = 0; i < 4; ++i) {
        const int gg = w * 256 + i * 64 + lane;
        const int r = gg >> 3, cg = gg & 7;
        srcA[i] = ET8 + (size_t)(d0 + r) * 32000 + (size_t)rank * SEG + kstart + cg * 16;
        srcB[i] = P8 + (size_t)(slot0 + r) * PSTR + kstart + cg * 16;  // pad rows are 0
        dst[i]  = (r * 8 + (cg ^ (r & 7))) * 16;
    }
    const int rh = w >> 1, th = w & 1, quad = lane >> 4, l15 = lane & 15;
    lds_u8* cA = (lds_u8*)sA0; lds_u8* cB = (lds_u8*)sB0;
    lds_u8* nA = (lds_u8*)sA1; lds_u8* nB = (lds_u8*)sB1;

    f32x4 acc[4][4] = {};
    PROLOG(cA, cB)
    for (int t = 1; t < nit; ++t) {
        PSTEP(cA, cB, nA, nB, t)
        lds_u8* tp;
        tp = cA; cA = nA; nA = tp;
        tp = cB; cB = nB; nB = tp;
    }
    CSTEP(cA, cB)

    ushort* Oz = Oacc + (size_t)z * MAXSLOTS * Dm;
    #pragma unroll
    for (int m = 0; m < 4; ++m) {
        const int d4 = d0 + rh*64 + m*16 + quad*4;
        #pragma unroll
        for (int n = 0; n < 4; ++n) {
            const int slot = slot0 + th*64 + n*16 + l15;
            unsigned long long u =
                  (unsigned long long)f2bf(acc[m][n][0])
                | ((unsigned long long)f2bf(acc[m][n][1]) << 16)
                | ((unsigned long long)f2bf(acc[m][n][2]) << 32)
                | ((unsigned long long)f2bf(acc[m][n][3]) << 48);
            *(unsigned long long*)(Oz + (size_t)slot * Dm + d4) = u;
        }
    }
}

// ---- K5: out[tok][d] = (sum_z Oacc[z][s][d]) / denom + q; denom from dpart ----
__global__ __launch_bounds__(256)
void k_final(const float* __restrict__ q, const int* __restrict__ iperm,
             const float* __restrict__ dpart, const ushort* __restrict__ Oacc,
             float* __restrict__ out) {
    const int tk = threadIdx.x >> 5;              // 8 tokens per block
    const int dl = threadIdx.x & 31;
    const int token = blockIdx.x * 8 + tk;
    const int s = iperm[token];
    float ds = 0.f;
    #pragma unroll
    for (int r = 0; r < 4; ++r) {
        const int j = dl + r * 32;
        if (j < 126) ds += dpart[(size_t)j * MAXSLOTS + s];
    }
    ds += __shfl_xor(ds, 1, 64);
    ds += __shfl_xor(ds, 2, 64);
    ds += __shfl_xor(ds, 4, 64);
    ds += __shfl_xor(ds, 8, 64);
    ds += __shfl_xor(ds, 16, 64);
    const float inv = 1.0f / ds;
    const float* qrow = q + (size_t)token * Dm;
    float* orow = out + (size_t)token * Dm;
    #pragma unroll
    for (int p = 0; p < 4; ++p) {
        const int d = p * 128 + dl * 4;
        float a0 = 0.f, a1 = 0.f, a2 = 0.f, a3 = 0.f;
        #pragma unroll
        for (int z = 0; z < 8; ++z) {
            unsigned long long u = *(const unsigned long long*)
                (Oacc + ((size_t)z * MAXSLOTS + s) * Dm + d);
            a0 += bf2f((ushort)u);
            a1 += bf2f((ushort)(u >> 16));
            a2 += bf2f((ushort)(u >> 32));
            a3 += bf2f((ushort)(u >> 48));
        }
        float4 qv = *(const float4*)(qrow + d);
        float4 o;
        o.x = a0 * inv + qv.x; o.y = a1 * inv + qv.y;
        o.z = a2 * inv + qv.z; o.w = a3 * inv + qv.w;
        *(float4*)(orow + d) = o;                 // coalesced
    }
}

extern "C" void kernel_launch(void* const* d_in, const int* in_sizes, int n_in,
                              void* d_out, int out_size, void* d_ws, size_t ws_size,
                              hipStream_t stream) {
    const float* q   = (const float*)d_in[0];
    const int*   xr  = (const int*)d_in[1];
    const float* emb = (const float*)d_in[2];
    float* out = (float*)d_out;
    char* ws = (char*)d_ws;

    int*    meta         = (int*)(ws + WS_META);
    int*    perm         = (int*)(ws + WS_PERM);
    int*    iperm        = (int*)(ws + WS_IPERM);
    unsigned char* Qb8   = (unsigned char*)(ws + WS_QB8);
    unsigned char* EB8   = (unsigned char*)(ws + WS_EB8);
    ushort* Oacc         = (ushort*)(ws + WS_OACC);
    unsigned char* ET8   = (unsigned char*)(ws + WS_ET8);
    unsigned char* P8    = (unsigned char*)(ws + WS_P8);
    float*  dpart        = (float*)(ws + WS_DPART);

    k_conv<<<dim3(251, 8), 256, 0, stream>>>(emb, EB8, ET8, xr, meta, perm, iperm);
    k_qb<<<MAXSLOTS / 8, 256, 0, stream>>>(q, perm, Qb8);
    k_qk<<<8 * 8 * MAXTILES, 256, 0, stream>>>(EB8, Qb8, meta, dpart, P8);
    k_pv<<<8 * 4 * MAXTILES, 256, 0, stream>>>(ET8, P8, meta, Oacc);
    k_final<<<NTOK / 8, 256, 0, stream>>>(q, iperm, dpart, Oacc, out);
}